// Round 12
// baseline (600.635 us; speedup 1.0000x reference)
//
#include <hip/hip_runtime.h>

// ---------------- problem constants ----------------
#define NTOK 8192      // B*T
#define CDIM 1024      // C
#define FDIM 2048      // F
#define NEXP 8         // E
#define CAP  16384     // per-expert list stride
#define NPAIR 16384    // N*K
#define MTCAP 32       // 32*128 = 4096 rows/expert capacity

typedef __bf16 bf16x8 __attribute__((ext_vector_type(8)));
typedef float  f32x4  __attribute__((ext_vector_type(4)));

__device__ __forceinline__ unsigned short f2bf(float f) {
    unsigned int u = __builtin_bit_cast(unsigned int, f);
    unsigned int r = (u + 0x7FFFu + ((u >> 16) & 1u)) >> 16;
    return (unsigned short)r;
}

__device__ __forceinline__ unsigned int pack2(float lo, float hi) {
    return ((unsigned int)f2bf(hi) << 16) | (unsigned int)f2bf(lo);
}

__device__ __forceinline__ float bflo(unsigned int u) {
    return __builtin_bit_cast(float, u << 16);
}
__device__ __forceinline__ float bfhi(unsigned int u) {
    return __builtin_bit_cast(float, u & 0xFFFF0000u);
}

__device__ __forceinline__ void gload_lds16(const void* g, void* l) {
    __builtin_amdgcn_global_load_lds(
        (const __attribute__((address_space(1))) unsigned int*)g,
        (__attribute__((address_space(3))) unsigned int*)l, 16, 0, 0);
}

#define BARRIER() asm volatile("s_barrier" ::: "memory")
#define WAIT_LGKM0() do { asm volatile("s_waitcnt lgkmcnt(0)" ::: "memory"); __builtin_amdgcn_sched_barrier(0); } while (0)
#define WAITVM(n) asm volatile("s_waitcnt vmcnt(" #n ")" ::: "memory")

// ---------------- fp32 -> bf16 bulk convert ----------------
__global__ void cvt_kernel(const float* __restrict__ s, unsigned short* __restrict__ d, long ngrp) {
    long i = (long)blockIdx.x * blockDim.x + threadIdx.x;
    long stride = (long)gridDim.x * blockDim.x;
    const float4* s4 = (const float4*)s;
    uint4* d4 = (uint4*)d;
    for (long g = i; g < ngrp; g += stride) {
        float4 a = s4[2 * g], b = s4[2 * g + 1];
        uint4 o;
        o.x = pack2(a.x, a.y); o.y = pack2(a.z, a.w);
        o.z = pack2(b.x, b.y); o.w = pack2(b.z, b.w);
        d4[g] = o;
    }
}

// ---------------- logits: top-2 + softmax weights, NO atomics ----------------
__global__ __launch_bounds__(256) void logits_kernel(
    const float* __restrict__ x, const float* __restrict__ Wr,
    float* __restrict__ wgt, int* __restrict__ eids)
{
    int w = threadIdx.x >> 6, l = threadIdx.x & 63;
    int t = blockIdx.x * 4 + w;
    const float* xr = x + (size_t)t * CDIM;
    float acc[NEXP];
    #pragma unroll
    for (int e = 0; e < NEXP; e++) acc[e] = 0.f;
    for (int c = l; c < CDIM; c += 64) {
        float xv = xr[c];
        #pragma unroll
        for (int e = 0; e < NEXP; e++) acc[e] += xv * Wr[e * CDIM + c];
    }
    #pragma unroll
    for (int e = 0; e < NEXP; e++)
        for (int off = 32; off > 0; off >>= 1) acc[e] += __shfl_down(acc[e], off);
    if (l == 0) {
        int i0 = 0; float l0 = acc[0];
        #pragma unroll
        for (int e = 1; e < NEXP; e++) if (acc[e] > l0) { l0 = acc[e]; i0 = e; }
        int i1 = -1; float l1 = -3.4e38f;
        #pragma unroll
        for (int e = 0; e < NEXP; e++) if (e != i0 && acc[e] > l1) { l1 = acc[e]; i1 = e; }
        float tv = __expf(l1 - l0);
        float den = 1.f + tv;
        wgt[2 * t] = 1.f / den;
        wgt[2 * t + 1] = tv / den;
        eids[t] = i0 | (i1 << 8);
    }
}

// ---------------- bucket: per-block LDS counters -> 8 global atomics/block ----------------
__global__ __launch_bounds__(256) void bucket_kernel(
    const int* __restrict__ eids, int* __restrict__ list, int* __restrict__ cnt)
{
    __shared__ int lcnt[NEXP];
    __shared__ int lbase[NEXP];
    int t = threadIdx.x;
    if (t < NEXP) lcnt[t] = 0;
    __syncthreads();
    int tok = blockIdx.x * 256 + t;
    int id = eids[tok];
    int e0 = id & 0xff, e1 = (id >> 8) & 0xff;
    int s0 = atomicAdd(&lcnt[e0], 1);
    int s1 = atomicAdd(&lcnt[e1], 1);
    __syncthreads();
    if (t < NEXP) lbase[t] = atomicAdd(&cnt[t], lcnt[t]);
    __syncthreads();
    list[e0 * CAP + lbase[e0] + s0] = 2 * tok;
    list[e1 * CAP + lbase[e1] + s1] = 2 * tok + 1;
}

// ---------------- offs: serial 8-entry prefix sum ----------------
__global__ void offs_kernel(const int* __restrict__ cnt, int* __restrict__ offs) {
    if (threadIdx.x == 0) {
        int a = 0;
        for (int e = 0; e < NEXP; e++) { offs[e] = a; a += cnt[e]; }
    }
}

// ---------------- pack: xg[offs[e]+s] = bf16(x[tok]); wgs[offs[e]+s] = wgt[p] ----------------
__global__ __launch_bounds__(256) void pack_kernel(
    const float* __restrict__ x, const int* __restrict__ list,
    const int* __restrict__ cnt, const int* __restrict__ offs,
    const float* __restrict__ wgt,
    unsigned short* __restrict__ xg, float* __restrict__ wgs)
{
    int e = blockIdx.y;
    int cnt_e = cnt[e];
    int s0 = blockIdx.x * 16;
    if (s0 >= cnt_e) return;
    int t = threadIdx.x;
    int sr = s0 + (t >> 4);
    if (sr >= cnt_e) return;
    int p = list[e * CAP + sr];
    int tok = p >> 1;
    if ((t & 15) == 0) wgs[offs[e] + sr] = wgt[p];
    const float4* src = (const float4*)(x + (size_t)tok * CDIM);
    uint2* dst = (uint2*)(xg + (size_t)(offs[e] + sr) * CDIM);
    int c = t & 15;
    #pragma unroll
    for (int i = 0; i < 16; i++) {
        float4 v = src[c + i * 16];
        uint2 o; o.x = pack2(v.x, v.y); o.y = pack2(v.z, v.w);
        dst[c + i * 16] = o;
    }
}

// Shared GEMM phase helper. Per phase:
//   ds_read A-quarter (4) [+ B-set (4)] -> issue 2 gloads -> barrier -> lgkm0
//   -> setprio(1) 16 MFMA setprio(0) -> [counted vmcnt] -> barrier.
// Stage order Ac0,Bc0,Ac1,Bc1 (2 loads each): vmcnt(4) at ph2 protects this
// tile's ks1 reads; vmcnt(4) at ph4 protects next tile's ks0 reads. Never 0 mid-loop.
#define PH(MH, KS, RB, STG, WV) do { \
    bf16x8 a_[4]; \
    _Pragma("unroll") for (int i_ = 0; i_ < 4; i_++) \
        a_[i_] = *(const bf16x8*)(cb + wm * 16384 + (KS) * 8192 + ((MH) * 4 + i_) * 1024 + lane_off); \
    if (RB) { _Pragma("unroll") for (int n_ = 0; n_ < 4; n_++) \
        b_[n_] = *(const bf16x8*)(cb + 32768 + (wn >> 1) * 16384 + (KS) * 8192 + (wn & 1) * 4096 + n_ * 1024 + lane_off); } \
    STG; \
    BARRIER(); \
    WAIT_LGKM0(); \
    __builtin_amdgcn_s_setprio(1); \
    _Pragma("unroll") for (int i_ = 0; i_ < 4; i_++) \
        _Pragma("unroll") for (int n_ = 0; n_ < 4; n_++) \
            acc[(MH) * 4 + i_][n_] = __builtin_amdgcn_mfma_f32_16x16x32_bf16(a_[i_], b_[n_], acc[(MH) * 4 + i_][n_], 0, 0, 0); \
    __builtin_amdgcn_s_setprio(0); \
    WV; \
    BARRIER(); \
} while (0)

// ============== GEMM1: 256 rows x [128 V | 128 G], BK=64, 4-phase counted-vmcnt ==============
// 8 waves 2Mx4N; wn 0,1 accumulate V, wn 2,3 accumulate G of the same f-cols.
// Epilogue: G passed to V-waves via 128 KB LDS exchange, fused silu*wgs store.
__global__ __launch_bounds__(512, 2) void gemm1_kernel(
    const unsigned short* __restrict__ xg,    // [NPAIR][CDIM] bf16, slot order
    const unsigned short* __restrict__ W1b,   // [E][2F][CDIM] bf16
    const float* __restrict__ wgs,            // [NPAIR] slot-order router weight
    unsigned short* __restrict__ act,         // [NPAIR][FDIM] bf16, slot order (weighted)
    const int* __restrict__ cnt, const int* __restrict__ offs)
{
    int e = blockIdx.z, mt = blockIdx.x, nt = blockIdx.y;
    int cnt_e = cnt[e];
    if (mt * 256 >= cnt_e) return;
    int off_e = offs[e];

    // dbuf 2 x 64KB; per buffer: A0[0,16K) A1[16K,32K) B0[32K,48K) B1[48K,64K); c-half +8K
    __shared__ __align__(16) char lds[131072];

    int t = threadIdx.x, l = t & 63, w = t >> 6;
    int wm = w >> 2, wn = w & 3;

    // staging: thread t = (row t>>2, slot t&3); source granule pre-swizzled (XOR (row>>1)&3)
    int sgz = ((t & 3) ^ ((t >> 3) & 3)) * 16;
    int dst = t * 16;

    const char *pA0, *pA1, *pB0, *pB1;
    {
        int r0 = min(mt * 256 + (t >> 2), cnt_e - 1);
        int r1 = min(mt * 256 + 128 + (t >> 2), cnt_e - 1);
        pA0 = (const char*)xg + (size_t)(off_e + r0) * 2048 + sgz;
        pA1 = (const char*)xg + (size_t)(off_e + r1) * 2048 + sgz;
        int f = nt * 128 + (t >> 2);
        pB0 = (const char*)W1b + ((size_t)e * 2 * FDIM + f) * 2048 + sgz;
        pB1 = pB0 + (size_t)FDIM * 2048;
    }

    int lane_off = (l & 15) * 64 + (((l >> 4) ^ (((l & 15) >> 1) & 3)) * 16);
    f32x4 acc[8][4] = {};

#define G1_AC(NB, KB, C) do { \
        gload_lds16(pA0 + (KB) + (C) * 64, (char*)lds + (NB) + (C) * 8192 + dst); \
        gload_lds16(pA1 + (KB) + (C) * 64, (char*)lds + (NB) + 16384 + (C) * 8192 + dst); \
    } while (0)
#define G1_BC(NB, KB, C) do { \
        gload_lds16(pB0 + (KB) + (C) * 64, (char*)lds + (NB) + 32768 + (C) * 8192 + dst); \
        gload_lds16(pB1 + (KB) + (C) * 64, (char*)lds + (NB) + 49152 + (C) * 8192 + dst); \
    } while (0)

    // prologue: tile 0 in strict order Ac0, Bc0, Ac1, Bc1
    G1_AC(0, 0, 0); G1_BC(0, 0, 0); G1_AC(0, 0, 1); G1_BC(0, 0, 1);
    WAITVM(4);
    BARRIER();

    for (int kt = 0; kt < 16; kt++) {
        const char* cb = (const char*)lds + (kt & 1) * 65536;
        int nb = ((kt + 1) & 1) * 65536;
        int kb = (kt + 1) * 128;
        bool stg = kt < 15;
        bf16x8 b_[4];
        PH(0, 0, true,  { if (stg) G1_AC(nb, kb, 0); }, {});
        PH(1, 0, false, { if (stg) G1_BC(nb, kb, 0); }, { if (kt == 15) { WAITVM(0); } else { WAITVM(4); } });
        PH(1, 1, true,  { if (stg) G1_AC(nb, kb, 1); }, {});
        PH(0, 1, false, { if (stg) G1_BC(nb, kb, 1); }, { if (kt < 15) { WAITVM(4); } });
    }
#undef G1_AC
#undef G1_BC

    // ---- epilogue: G-waves (wn>=2) hand their acc to the matching V-wave via LDS ----
    float* exch = (float*)lds;
    if (wn >= 2) {
        int base = (wm * 2 + (wn - 2)) * 8192;   // floats
        #pragma unroll
        for (int m = 0; m < 8; m++)
            #pragma unroll
            for (int n = 0; n < 4; n++)
                *(f32x4*)(exch + base + (m * 4 + n) * 256 + l * 4) = acc[m][n];
    }
    __syncthreads();
    if (wn < 2) {
        int base = (wm * 2 + wn) * 8192;
        int colF = nt * 128 + wn * 64 + (l & 15);
        int rowB = mt * 256 + wm * 128 + ((l >> 4) * 4);
        #pragma unroll
        for (int m = 0; m < 8; m++) {
            #pragma unroll
            for (int n = 0; n < 4; n++) {
                f32x4 g4 = *(const f32x4*)(exch + base + (m * 4 + n) * 256 + l * 4);
                int col = colF + n * 16;
                #pragma unroll
                for (int r = 0; r < 4; r++) {
                    int srow = rowB + m * 16 + r;
                    if (srow < cnt_e) {
                        float wsc = wgs[off_e + srow];
                        float g = g4[r];
                        float v = acc[m][n][r];
                        float aa = wsc * v * g / (1.f + __expf(-g));
                        act[(size_t)(off_e + srow) * FDIM + col] = f2bf(aa);
                    }
                }
            }
        }
    }
}

// ============== GEMM2: 256x256, BK=64, 4-phase counted-vmcnt, K=2048 ==============
__global__ __launch_bounds__(512, 2) void gemm2_kernel(
    const unsigned short* __restrict__ act,   // [NPAIR][FDIM] bf16, slot order (weighted)
    const unsigned short* __restrict__ W2b,   // [E][CDIM][FDIM] bf16
    const int* __restrict__ list, const int* __restrict__ cnt,
    const int* __restrict__ offs,
    unsigned short* __restrict__ eob)         // [NPAIR][CDIM] bf16, pair order
{
    int e = blockIdx.z, mt = blockIdx.x, nt = blockIdx.y;
    int cnt_e = cnt[e];
    if (mt * 256 >= cnt_e) return;
    int off_e = offs[e];
    const int* le = list + e * CAP;

    __shared__ __align__(16) char lds[131072];

    int t = threadIdx.x, l = t & 63, w = t >> 6;
    int wm = w >> 2, wn = w & 3;

    int sgz = ((t & 3) ^ ((t >> 3) & 3)) * 16;
    int dst = t * 16;

    const char *pA0, *pA1, *pB0, *pB1;
    {
        int r0 = min(mt * 256 + (t >> 2), cnt_e - 1);
        int r1 = min(mt * 256 + 128 + (t >> 2), cnt_e - 1);
        pA0 = (const char*)act + (size_t)(off_e + r0) * 4096 + sgz;
        pA1 = (const char*)act + (size_t)(off_e + r1) * 4096 + sgz;
        int c0 = nt * 256 + (t >> 2);
        pB0 = (const char*)W2b + ((size_t)e * CDIM + c0) * 4096 + sgz;
        pB1 = pB0 + (size_t)128 * 4096;
    }

    int lane_off = (l & 15) * 64 + (((l >> 4) ^ (((l & 15) >> 1) & 3)) * 16);
    f32x4 acc[8][4] = {};

#define G2_AC(NB, KB, C) do { \
        gload_lds16(pA0 + (KB) + (C) * 64, (char*)lds + (NB) + (C) * 8192 + dst); \
        gload_lds16(pA1 + (KB) + (C) * 64, (char*)lds + (NB) + 16384 + (C) * 8192 + dst); \
    } while (0)
#define G2_BC(NB, KB, C) do { \
        gload_lds16(pB0 + (KB) + (C) * 64, (char*)lds + (NB) + 32768 + (C) * 8192 + dst); \
        gload_lds16(pB1 + (KB) + (C) * 64, (char*)lds + (NB) + 49152 + (C) * 8192 + dst); \
    } while (0)

    G2_AC(0, 0, 0); G2_BC(0, 0, 0); G2_AC(0, 0, 1); G2_BC(0, 0, 1);
    WAITVM(4);
    BARRIER();

    for (int kt = 0; kt < 32; kt++) {
        const char* cb = (const char*)lds + (kt & 1) * 65536;
        int nb = ((kt + 1) & 1) * 65536;
        int kb = (kt + 1) * 128;
        bool stg = kt < 31;
        bf16x8 b_[4];
        PH(0, 0, true,  { if (stg) G2_AC(nb, kb, 0); }, {});
        PH(1, 0, false, { if (stg) G2_BC(nb, kb, 0); }, { if (kt == 31) { WAITVM(0); } else { WAITVM(4); } });
        PH(1, 1, true,  { if (stg) G2_AC(nb, kb, 1); }, {});
        PH(0, 1, false, { if (stg) G2_BC(nb, kb, 1); }, { if (kt < 31) { WAITVM(4); } });
    }
#undef G2_AC
#undef G2_BC

    int colC = nt * 256 + wn * 64 + (l & 15);
    int rowB = mt * 256 + wm * 128 + ((l >> 4) * 4);
    #pragma unroll
    for (int m = 0; m < 8; m++) {
        #pragma unroll
        for (int r = 0; r < 4; r++) {
            int srow = rowB + m * 16 + r;
            if (srow < cnt_e) {
                int p = le[srow];
                #pragma unroll
                for (int n = 0; n < 4; n++)
                    eob[(size_t)p * CDIM + colC + n * 16] = f2bf(acc[m][n][r]);
            }
        }
    }
}

// ---------------- combine: out[t] = eo[2t] + eo[2t+1] (weights pre-folded) ----------------
__global__ __launch_bounds__(256) void combine_kernel(
    const unsigned short* __restrict__ eob, float* __restrict__ out)
{
    const long NG = (long)NTOK * (CDIM / 4);
    long i = (long)blockIdx.x * blockDim.x + threadIdx.x;
    long stride = (long)gridDim.x * blockDim.x;
    float4* out4 = (float4*)out;
    for (long g = i; g < NG; g += stride) {
        long t = g >> 8;
        long j = g & 255;
        uint2 a = ((const uint2*)(eob + (size_t)(2 * t) * CDIM))[j];
        uint2 b = ((const uint2*)(eob + (size_t)(2 * t + 1) * CDIM))[j];
        float4 o;
        o.x = bflo(a.x) + bflo(b.x);
        o.y = bfhi(a.x) + bfhi(b.x);
        o.z = bflo(a.y) + bflo(b.y);
        o.w = bfhi(a.y) + bfhi(b.y);
        out4[g] = o;
    }
}

// ---------------- launch ----------------
extern "C" void kernel_launch(void* const* d_in, const int* in_sizes, int n_in,
                              void* d_out, int out_size, void* d_ws, size_t ws_size,
                              hipStream_t stream) {
    const float* x  = (const float*)d_in[0];
    const float* Wr = (const float*)d_in[1];
    const float* W1 = (const float*)d_in[2];
    const float* W2 = (const float*)d_in[3];
    float* out = (float*)d_out;
    char* ws = (char*)d_ws;

    const size_t OFF_XG   = 0;
    const size_t OFF_W1B  = OFF_XG  + (size_t)NPAIR * CDIM * 2;           // 33,554,432
    const size_t OFF_ACT  = OFF_W1B + (size_t)NEXP * 2 * FDIM * CDIM * 2; // +67,108,864
    const size_t OFF_LIST = OFF_ACT + (size_t)NPAIR * FDIM * 2;           // +67,108,864
    const size_t OFF_WGT  = OFF_LIST + (size_t)NEXP * CAP * 4;
    const size_t OFF_WGS  = OFF_WGT + (size_t)NPAIR * 4;
    const size_t OFF_CNT  = OFF_WGS + (size_t)NPAIR * 4;
    const size_t OFF_OFFS = OFF_CNT + 32;
    const size_t OFF_EIDS = OFF_OFFS + 32;

    unsigned short* xg  = (unsigned short*)(ws + OFF_XG);
    unsigned short* W1b = (unsigned short*)(ws + OFF_W1B);
    unsigned short* act = (unsigned short*)(ws + OFF_ACT);
    int*   list = (int*)(ws + OFF_LIST);
    float* wgt  = (float*)(ws + OFF_WGT);
    float* wgs  = (float*)(ws + OFF_WGS);
    int*   cnt  = (int*)(ws + OFF_CNT);
    int*   offs = (int*)(ws + OFF_OFFS);
    int*   eids = (int*)(ws + OFF_EIDS);
    // overlays (dead-after-gemm1 regions):
    unsigned short* W2b = (unsigned short*)(ws + OFF_W1B);  // 33.5 MB <= 67 MB region
    unsigned short* eob = (unsigned short*)(ws + OFF_XG);   // 33.5 MB exactly

    hipMemsetAsync(cnt, 0, NEXP * sizeof(int), stream);

    cvt_kernel<<<4096, 256, 0, stream>>>(W1, W1b, (long)NEXP * 2 * FDIM * CDIM / 8);
    logits_kernel<<<NTOK / 4, 256, 0, stream>>>(x, Wr, wgt, eids);
    bucket_kernel<<<NTOK / 256, 256, 0, stream>>>(eids, list, cnt);
    offs_kernel<<<1, 64, 0, stream>>>(cnt, offs);
    pack_kernel<<<dim3(256, NEXP), 256, 0, stream>>>(x, list, cnt, offs, wgt, xg, wgs);

    gemm1_kernel<<<dim3(MTCAP / 2, FDIM / 128, NEXP), 512, 0, stream>>>(xg, W1b, wgs, act, cnt, offs);

    cvt_kernel<<<4096, 256, 0, stream>>>(W2, W2b, (long)NEXP * CDIM * FDIM / 8);

    gemm2_kernel<<<dim3(MTCAP / 2, CDIM / 256, NEXP), 512, 0, stream>>>(act, W2b, list, cnt, offs, eob);
    combine_kernel<<<2048, 256, 0, stream>>>(eob, out);
}

// Round 13
// 352.827 us; speedup vs baseline: 1.7024x; 1.7024x over previous
//
#include <hip/hip_runtime.h>

// ---------------- problem constants ----------------
#define NTOK 8192      // B*T
#define CDIM 1024      // C
#define FDIM 2048      // F
#define NEXP 8         // E
#define CAP  16384     // per-expert list stride
#define NPAIR 16384    // N*K
#define MTCAP 32       // 32*128 = 4096 rows/expert capacity

typedef __bf16 bf16x8 __attribute__((ext_vector_type(8)));
typedef float  f32x4  __attribute__((ext_vector_type(4)));

__device__ __forceinline__ unsigned short f2bf(float f) {
    unsigned int u = __builtin_bit_cast(unsigned int, f);
    unsigned int r = (u + 0x7FFFu + ((u >> 16) & 1u)) >> 16;
    return (unsigned short)r;
}

__device__ __forceinline__ unsigned int pack2(float lo, float hi) {
    return ((unsigned int)f2bf(hi) << 16) | (unsigned int)f2bf(lo);
}

__device__ __forceinline__ float bflo(unsigned int u) {
    return __builtin_bit_cast(float, u << 16);
}
__device__ __forceinline__ float bfhi(unsigned int u) {
    return __builtin_bit_cast(float, u & 0xFFFF0000u);
}

__device__ __forceinline__ void gload_lds16(const void* g, void* l) {
    __builtin_amdgcn_global_load_lds(
        (const __attribute__((address_space(1))) unsigned int*)g,
        (__attribute__((address_space(3))) unsigned int*)l, 16, 0, 0);
}

#define BARRIER() asm volatile("s_barrier" ::: "memory")
#define WAIT_LGKM0() do { asm volatile("s_waitcnt lgkmcnt(0)" ::: "memory"); __builtin_amdgcn_sched_barrier(0); } while (0)
#define WAITVM0() asm volatile("s_waitcnt vmcnt(0)" ::: "memory")

// ---------------- fp32 -> bf16 bulk convert ----------------
__global__ void cvt_kernel(const float* __restrict__ s, unsigned short* __restrict__ d, long ngrp) {
    long i = (long)blockIdx.x * blockDim.x + threadIdx.x;
    long stride = (long)gridDim.x * blockDim.x;
    const float4* s4 = (const float4*)s;
    uint4* d4 = (uint4*)d;
    for (long g = i; g < ngrp; g += stride) {
        float4 a = s4[2 * g], b = s4[2 * g + 1];
        uint4 o;
        o.x = pack2(a.x, a.y); o.y = pack2(a.z, a.w);
        o.z = pack2(b.x, b.y); o.w = pack2(b.z, b.w);
        d4[g] = o;
    }
}

// ---------------- logits: top-2 + softmax weights, float4 vectorized, NO atomics ----------------
__global__ __launch_bounds__(256) void logits_kernel(
    const float* __restrict__ x, const float* __restrict__ Wr,
    float* __restrict__ wgt, int* __restrict__ eids)
{
    int w = threadIdx.x >> 6, l = threadIdx.x & 63;
    int t = blockIdx.x * 4 + w;
    const float4* xr = (const float4*)(x + (size_t)t * CDIM);
    const float4* Wr4 = (const float4*)Wr;
    float acc[NEXP];
    #pragma unroll
    for (int e = 0; e < NEXP; e++) acc[e] = 0.f;
    #pragma unroll
    for (int i = 0; i < 4; i++) {
        int idx = l + 64 * i;          // float4 index within row (256 total)
        float4 xv = xr[idx];
        #pragma unroll
        for (int e = 0; e < NEXP; e++) {
            float4 wv = Wr4[e * 256 + idx];
            acc[e] += xv.x * wv.x + xv.y * wv.y + xv.z * wv.z + xv.w * wv.w;
        }
    }
    #pragma unroll
    for (int e = 0; e < NEXP; e++)
        for (int off = 32; off > 0; off >>= 1) acc[e] += __shfl_down(acc[e], off);
    if (l == 0) {
        int i0 = 0; float l0 = acc[0];
        #pragma unroll
        for (int e = 1; e < NEXP; e++) if (acc[e] > l0) { l0 = acc[e]; i0 = e; }
        int i1 = -1; float l1 = -3.4e38f;
        #pragma unroll
        for (int e = 0; e < NEXP; e++) if (e != i0 && acc[e] > l1) { l1 = acc[e]; i1 = e; }
        float tv = __expf(l1 - l0);
        float den = 1.f + tv;
        wgt[2 * t] = 1.f / den;
        wgt[2 * t + 1] = tv / den;
        eids[t] = i0 | (i1 << 8);
    }
}

// ---------------- bucket: per-block LDS counters -> 8 global atomics/block ----------------
__global__ __launch_bounds__(256) void bucket_kernel(
    const int* __restrict__ eids, int* __restrict__ list, int* __restrict__ cnt)
{
    __shared__ int lcnt[NEXP];
    __shared__ int lbase[NEXP];
    int t = threadIdx.x;
    if (t < NEXP) lcnt[t] = 0;
    __syncthreads();
    int tok = blockIdx.x * 256 + t;
    int id = eids[tok];
    int e0 = id & 0xff, e1 = (id >> 8) & 0xff;
    int s0 = atomicAdd(&lcnt[e0], 1);
    int s1 = atomicAdd(&lcnt[e1], 1);
    __syncthreads();
    if (t < NEXP) lbase[t] = atomicAdd(&cnt[t], lcnt[t]);
    __syncthreads();
    list[e0 * CAP + lbase[e0] + s0] = 2 * tok;
    list[e1 * CAP + lbase[e1] + s1] = 2 * tok + 1;
}

// ---------------- offs: serial 8-entry prefix sum ----------------
__global__ void offs_kernel(const int* __restrict__ cnt, int* __restrict__ offs) {
    if (threadIdx.x == 0) {
        int a = 0;
        for (int e = 0; e < NEXP; e++) { offs[e] = a; a += cnt[e]; }
    }
}

// ---------------- pack: xg[offs[e]+s] = bf16(x[tok]); wgs[offs[e]+s] = wgt[p] ----------------
// 16 rows/block, 16 threads/row; uint4 (16B) stores.
__global__ __launch_bounds__(256) void pack_kernel(
    const float* __restrict__ x, const int* __restrict__ list,
    const int* __restrict__ cnt, const int* __restrict__ offs,
    const float* __restrict__ wgt,
    unsigned short* __restrict__ xg, float* __restrict__ wgs)
{
    int e = blockIdx.y;
    int cnt_e = cnt[e];
    int s0 = blockIdx.x * 16;
    if (s0 >= cnt_e) return;
    int t = threadIdx.x;
    int sr = s0 + (t >> 4);
    if (sr >= cnt_e) return;
    int p = list[e * CAP + sr];
    int tok = p >> 1;
    if ((t & 15) == 0) wgs[offs[e] + sr] = wgt[p];
    const float4* src = (const float4*)(x + (size_t)tok * CDIM);
    uint4* dst = (uint4*)(xg + (size_t)(offs[e] + sr) * CDIM);
    int c = t & 15;
    #pragma unroll
    for (int i = 0; i < 8; i++) {
        float4 a = src[2 * c + i * 32];
        float4 b = src[2 * c + 1 + i * 32];
        uint4 o;
        o.x = pack2(a.x, a.y); o.y = pack2(a.z, a.w);
        o.z = pack2(b.x, b.y); o.w = pack2(b.z, b.w);
        dst[c + i * 16] = o;
    }
}

// ============== GEMM1: dense grouped, 128x64(V+G), BK=64, stage-early drain-late ==============
// Round-10 proven structure (151 us, 910 TF) - UNCHANGED.
__global__ __launch_bounds__(256, 2) void gemm1_kernel(
    const unsigned short* __restrict__ xg,    // [NPAIR][CDIM] bf16, slot order
    const unsigned short* __restrict__ W1b,   // [E][2F][CDIM] bf16
    const float* __restrict__ wgs,            // [NPAIR] slot-order router weight
    unsigned short* __restrict__ act,         // [NPAIR][FDIM] bf16, slot order (weighted)
    const int* __restrict__ cnt, const int* __restrict__ offs)
{
    int e = blockIdx.z, nt = blockIdx.x, mt = blockIdx.y;
    int cnt_e = cnt[e];
    if (mt * 128 >= cnt_e) return;
    int off_e = offs[e];

    // LDS 32KB: A k0 [0,8K) | A k1 [8K,16K) | Bv k0/k1 [16K,24K) | Bg k0/k1 [24K,32K)
    __shared__ __align__(16) char lds[32768];

    int t = threadIdx.x, l = t & 63, w = t >> 6;
    int wave_m = w >> 1, wave_n = w & 1;

    int c2s = ((t & 3) * 16) ^ (((t >> 5) & 1) << 5);
    int dst = t * 16;

    const char *sA0, *sA1, *sBv, *sBg;
    {
        int r0 = min(mt * 128 + (t >> 2), cnt_e - 1);
        int r1 = min(mt * 128 + 64 + (t >> 2), cnt_e - 1);
        sA0 = (const char*)xg + (size_t)(off_e + r0) * 2048 + c2s;
        sA1 = (const char*)xg + (size_t)(off_e + r1) * 2048 + c2s;
        int f = nt * 64 + (t >> 2);
        sBv = (const char*)W1b + ((size_t)e * 2 * FDIM + f) * 2048 + c2s;
        sBg = sBv + (size_t)FDIM * 2048;
    }

    int lane_off = (l & 15) * 64 + (((l >> 4) * 16) ^ (((l >> 3) & 1) << 5));
    f32x4 accV[4][2] = {}, accG[4][2] = {};

#define G1_STAGE(KB) do { \
        gload_lds16(sA0 + (KB),      (char*)lds + dst); \
        gload_lds16(sA1 + (KB),      (char*)lds + 4096 + dst); \
        gload_lds16(sA0 + (KB) + 64, (char*)lds + 8192 + dst); \
        gload_lds16(sA1 + (KB) + 64, (char*)lds + 12288 + dst); \
        gload_lds16(sBv + (KB),      (char*)lds + 16384 + dst); \
        gload_lds16(sBv + (KB) + 64, (char*)lds + 20480 + dst); \
        gload_lds16(sBg + (KB),      (char*)lds + 24576 + dst); \
        gload_lds16(sBg + (KB) + 64, (char*)lds + 28672 + dst); \
    } while (0)

    G1_STAGE(0);   // prologue: tile 0

    #pragma unroll
    for (int kt = 0; kt < 16; kt++) {
        WAITVM0();
        BARRIER();

        bf16x8 af[2][4], bv[2][2], bg[2][2];
        #pragma unroll
        for (int h = 0; h < 2; h++) {
            #pragma unroll
            for (int m = 0; m < 4; m++)
                af[h][m] = *(const bf16x8*)((char*)lds + h * 8192 + (wave_m * 4 + m) * 1024 + lane_off);
            #pragma unroll
            for (int n = 0; n < 2; n++) {
                bv[h][n] = *(const bf16x8*)((char*)lds + 16384 + h * 4096 + (wave_n * 2 + n) * 1024 + lane_off);
                bg[h][n] = *(const bf16x8*)((char*)lds + 24576 + h * 4096 + (wave_n * 2 + n) * 1024 + lane_off);
            }
        }
        WAIT_LGKM0();
        BARRIER();           // all waves done reading LDS -> safe to overwrite

        if (kt != 15) { int kb = (kt + 1) * 128; G1_STAGE(kb); }
        __builtin_amdgcn_sched_barrier(0);

        __builtin_amdgcn_s_setprio(1);
        #pragma unroll
        for (int h = 0; h < 2; h++)
            #pragma unroll
            for (int m = 0; m < 4; m++)
                #pragma unroll
                for (int n = 0; n < 2; n++) {
                    accV[m][n] = __builtin_amdgcn_mfma_f32_16x16x32_bf16(af[h][m], bv[h][n], accV[m][n], 0, 0, 0);
                    accG[m][n] = __builtin_amdgcn_mfma_f32_16x16x32_bf16(af[h][m], bg[h][n], accG[m][n], 0, 0, 0);
                }
        __builtin_amdgcn_s_setprio(0);
    }
#undef G1_STAGE

    // epilogue: silu-gate * router weight, bf16 store (slot order)
    int colF = nt * 64 + wave_n * 32 + (l & 15);
    int rowB = mt * 128 + wave_m * 64 + ((l >> 4) * 4);
    #pragma unroll
    for (int m = 0; m < 4; m++) {
        #pragma unroll
        for (int r = 0; r < 4; r++) {
            int srow = rowB + m * 16 + r;
            if (srow < cnt_e) {
                float wsc = wgs[off_e + srow];
                #pragma unroll
                for (int n = 0; n < 2; n++) {
                    float g = accG[m][n][r];
                    float v = accV[m][n][r];
                    float aa = wsc * v * g / (1.f + __expf(-g));
                    act[(size_t)(off_e + srow) * FDIM + colF + n * 16] = f2bf(aa);
                }
            }
        }
    }
}

// ============== GEMM2: dense grouped, 128x128, SPLIT-K=2, BK=64 ==============
// Round-10 loop structure; each block computes one 1024-wide K-half -> eob[kh].
// 2048 active blocks (2x round 10) amortizes tail + boosts TLP.
__global__ __launch_bounds__(256, 2) void gemm2_kernel(
    const unsigned short* __restrict__ act,   // [NPAIR][FDIM] bf16, slot order (weighted)
    const unsigned short* __restrict__ W2b,   // [E][CDIM][FDIM] bf16
    const int* __restrict__ list, const int* __restrict__ cnt,
    const int* __restrict__ offs,
    unsigned short* __restrict__ eob0,        // [NPAIR][CDIM] bf16, pair order, K-half 0
    unsigned short* __restrict__ eob1)        // [NPAIR][CDIM] bf16, pair order, K-half 1
{
    int e = blockIdx.z, mt = blockIdx.y;
    int nt = blockIdx.x & 7, kh = blockIdx.x >> 3;
    int cnt_e = cnt[e];
    if (mt * 128 >= cnt_e) return;
    int off_e = offs[e];
    const int* le = list + e * CAP;

    __shared__ __align__(16) char lds[32768];

    int t = threadIdx.x, l = t & 63, w = t >> 6;
    int wave_m = w >> 1, wave_n = w & 1;

    int c2s = ((t & 3) * 16) ^ (((t >> 5) & 1) << 5);
    int dst = t * 16;

    const char *sA0, *sA1, *sB0, *sB1;
    {
        int r0 = min(mt * 128 + (t >> 2), cnt_e - 1);
        int r1 = min(mt * 128 + 64 + (t >> 2), cnt_e - 1);
        size_t khb = (size_t)kh * 2048;   // 1024 elems * 2B
        sA0 = (const char*)act + (size_t)(off_e + r0) * 4096 + khb + c2s;
        sA1 = (const char*)act + (size_t)(off_e + r1) * 4096 + khb + c2s;
        int c0 = nt * 128 + (t >> 2);
        sB0 = (const char*)W2b + ((size_t)e * CDIM + c0) * 4096 + khb + c2s;
        sB1 = sB0 + (size_t)64 * 4096;
    }

    int lane_off = (l & 15) * 64 + (((l >> 4) * 16) ^ (((l >> 3) & 1) << 5));
    f32x4 acc[4][4] = {};

#define G2_STAGE(KB) do { \
        gload_lds16(sA0 + (KB),      (char*)lds + dst); \
        gload_lds16(sA1 + (KB),      (char*)lds + 4096 + dst); \
        gload_lds16(sA0 + (KB) + 64, (char*)lds + 8192 + dst); \
        gload_lds16(sA1 + (KB) + 64, (char*)lds + 12288 + dst); \
        gload_lds16(sB0 + (KB),      (char*)lds + 16384 + dst); \
        gload_lds16(sB1 + (KB),      (char*)lds + 20480 + dst); \
        gload_lds16(sB0 + (KB) + 64, (char*)lds + 24576 + dst); \
        gload_lds16(sB1 + (KB) + 64, (char*)lds + 28672 + dst); \
    } while (0)

    G2_STAGE(0);

    #pragma unroll
    for (int kt = 0; kt < 16; kt++) {
        WAITVM0();
        BARRIER();

        bf16x8 af[2][4], bf[2][4];
        #pragma unroll
        for (int h = 0; h < 2; h++) {
            #pragma unroll
            for (int m = 0; m < 4; m++)
                af[h][m] = *(const bf16x8*)((char*)lds + h * 8192 + (wave_m * 4 + m) * 1024 + lane_off);
            #pragma unroll
            for (int n = 0; n < 4; n++)
                bf[h][n] = *(const bf16x8*)((char*)lds + 16384 + h * 8192 + (wave_n * 4 + n) * 1024 + lane_off);
        }
        WAIT_LGKM0();
        BARRIER();

        if (kt != 15) { int kb = (kt + 1) * 128; G2_STAGE(kb); }
        __builtin_amdgcn_sched_barrier(0);

        __builtin_amdgcn_s_setprio(1);
        #pragma unroll
        for (int h = 0; h < 2; h++)
            #pragma unroll
            for (int m = 0; m < 4; m++)
                #pragma unroll
                for (int n = 0; n < 4; n++)
                    acc[m][n] = __builtin_amdgcn_mfma_f32_16x16x32_bf16(af[h][m], bf[h][n], acc[m][n], 0, 0, 0);
        __builtin_amdgcn_s_setprio(0);
    }
#undef G2_STAGE

    unsigned short* eob = kh ? eob1 : eob0;
    int colC = nt * 128 + wave_n * 64 + (l & 15);
    int rowB = mt * 128 + wave_m * 64 + ((l >> 4) * 4);
    #pragma unroll
    for (int m = 0; m < 4; m++) {
        #pragma unroll
        for (int r = 0; r < 4; r++) {
            int srow = rowB + m * 16 + r;
            if (srow < cnt_e) {
                int p = le[srow];
                #pragma unroll
                for (int n = 0; n < 4; n++)
                    eob[(size_t)p * CDIM + colC + n * 16] = f2bf(acc[m][n][r]);
            }
        }
    }
}

// ---------------- combine: out[t] = sum over {pair0,pair1} x {kh0,kh1} ----------------
__global__ __launch_bounds__(256) void combine_kernel(
    const unsigned short* __restrict__ eob0, const unsigned short* __restrict__ eob1,
    float* __restrict__ out)
{
    const long NG = (long)NTOK * (CDIM / 4);
    long i = (long)blockIdx.x * blockDim.x + threadIdx.x;
    long stride = (long)gridDim.x * blockDim.x;
    float4* out4 = (float4*)out;
    for (long g = i; g < NG; g += stride) {
        long t = g >> 8;
        long j = g & 255;
        uint2 a0 = ((const uint2*)(eob0 + (size_t)(2 * t) * CDIM))[j];
        uint2 b0 = ((const uint2*)(eob0 + (size_t)(2 * t + 1) * CDIM))[j];
        uint2 a1 = ((const uint2*)(eob1 + (size_t)(2 * t) * CDIM))[j];
        uint2 b1 = ((const uint2*)(eob1 + (size_t)(2 * t + 1) * CDIM))[j];
        float4 o;
        o.x = (bflo(a0.x) + bflo(a1.x)) + (bflo(b0.x) + bflo(b1.x));
        o.y = (bfhi(a0.x) + bfhi(a1.x)) + (bfhi(b0.x) + bfhi(b1.x));
        o.z = (bflo(a0.y) + bflo(a1.y)) + (bflo(b0.y) + bflo(b1.y));
        o.w = (bfhi(a0.y) + bfhi(a1.y)) + (bfhi(b0.y) + bfhi(b1.y));
        out4[g] = o;
    }
}

// ---------------- launch ----------------
extern "C" void kernel_launch(void* const* d_in, const int* in_sizes, int n_in,
                              void* d_out, int out_size, void* d_ws, size_t ws_size,
                              hipStream_t stream) {
    const float* x  = (const float*)d_in[0];
    const float* Wr = (const float*)d_in[1];
    const float* W1 = (const float*)d_in[2];
    const float* W2 = (const float*)d_in[3];
    float* out = (float*)d_out;
    char* ws = (char*)d_ws;

    // Workspace (~168.6 MB):
    //   [0, 33.5M)      xg (slot order)      -> eob0 (pair order) after gemm1
    //   [33.5M, 100.7M) W1b                  -> [W2b 33.5M | eob1 33.5M] after gemm1
    //   [100.7M,167.8M) act (slot order)
    //   then list / wgt / wgs / cnt / offs / eids
    const size_t OFF_XG   = 0;
    const size_t OFF_W1B  = OFF_XG  + (size_t)NPAIR * CDIM * 2;           // 33,554,432
    const size_t OFF_ACT  = OFF_W1B + (size_t)NEXP * 2 * FDIM * CDIM * 2; // +67,108,864
    const size_t OFF_LIST = OFF_ACT + (size_t)NPAIR * FDIM * 2;           // +67,108,864
    const size_t OFF_WGT  = OFF_LIST + (size_t)NEXP * CAP * 4;
    const size_t OFF_WGS  = OFF_WGT + (size_t)NPAIR * 4;
    const size_t OFF_CNT  = OFF_WGS + (size_t)NPAIR * 4;
    const size_t OFF_OFFS = OFF_CNT + 32;
    const size_t OFF_EIDS = OFF_OFFS + 32;

    unsigned short* xg  = (unsigned short*)(ws + OFF_XG);
    unsigned short* W1b = (unsigned short*)(ws + OFF_W1B);
    unsigned short* act = (unsigned short*)(ws + OFF_ACT);
    int*   list = (int*)(ws + OFF_LIST);
    float* wgt  = (float*)(ws + OFF_WGT);
    float* wgs  = (float*)(ws + OFF_WGS);
    int*   cnt  = (int*)(ws + OFF_CNT);
    int*   offs = (int*)(ws + OFF_OFFS);
    int*   eids = (int*)(ws + OFF_EIDS);
    // overlays (dead-after-gemm1 regions):
    unsigned short* W2b  = (unsigned short*)(ws + OFF_W1B);              // 33.5 MB
    unsigned short* eob1 = (unsigned short*)(ws + OFF_W1B + (size_t)NPAIR * CDIM * 2); // 33.5 MB
    unsigned short* eob0 = (unsigned short*)(ws + OFF_XG);               // 33.5 MB

    hipMemsetAsync(cnt, 0, NEXP * sizeof(int), stream);

    cvt_kernel<<<4096, 256, 0, stream>>>(W1, W1b, (long)NEXP * 2 * FDIM * CDIM / 8);
    logits_kernel<<<NTOK / 4, 256, 0, stream>>>(x, Wr, wgt, eids);
    bucket_kernel<<<NTOK / 256, 256, 0, stream>>>(eids, list, cnt);
    offs_kernel<<<1, 64, 0, stream>>>(cnt, offs);
    pack_kernel<<<dim3(256, NEXP), 256, 0, stream>>>(x, list, cnt, offs, wgt, xg, wgs);

    gemm1_kernel<<<dim3(FDIM / 64, MTCAP, NEXP), 256, 0, stream>>>(xg, W1b, wgs, act, cnt, offs);

    cvt_kernel<<<4096, 256, 0, stream>>>(W2, W2b, (long)NEXP * CDIM * FDIM / 8);

    gemm2_kernel<<<dim3(16, MTCAP, NEXP), 256, 0, stream>>>(act, W2b, list, cnt, offs, eob0, eob1);
    combine_kernel<<<2048, 256, 0, stream>>>(eob0, eob1, out);
}

// Round 14
// 347.835 us; speedup vs baseline: 1.7268x; 1.0143x over previous
//
#include <hip/hip_runtime.h>

// ---------------- problem constants ----------------
#define NTOK 8192      // B*T
#define CDIM 1024      // C
#define FDIM 2048      // F
#define NEXP 8         // E
#define CAP  16384     // per-expert list stride
#define NPAIR 16384    // N*K
#define MTCAP 32       // 32*128 = 4096 rows/expert capacity

typedef __bf16 bf16x8 __attribute__((ext_vector_type(8)));
typedef float  f32x4  __attribute__((ext_vector_type(4)));

__device__ __forceinline__ unsigned short f2bf(float f) {
    unsigned int u = __builtin_bit_cast(unsigned int, f);
    unsigned int r = (u + 0x7FFFu + ((u >> 16) & 1u)) >> 16;
    return (unsigned short)r;
}

__device__ __forceinline__ unsigned int pack2(float lo, float hi) {
    return ((unsigned int)f2bf(hi) << 16) | (unsigned int)f2bf(lo);
}

__device__ __forceinline__ float bflo(unsigned int u) {
    return __builtin_bit_cast(float, u << 16);
}
__device__ __forceinline__ float bfhi(unsigned int u) {
    return __builtin_bit_cast(float, u & 0xFFFF0000u);
}

__device__ __forceinline__ void gload_lds16(const void* g, void* l) {
    __builtin_amdgcn_global_load_lds(
        (const __attribute__((address_space(1))) unsigned int*)g,
        (__attribute__((address_space(3))) unsigned int*)l, 16, 0, 0);
}

__device__ __forceinline__ int exp_off(const int* __restrict__ cnt, int e) {
    int o = 0;
    #pragma unroll
    for (int i = 0; i < NEXP; i++) o += (i < e) ? cnt[i] : 0;
    return o;
}

#define BARRIER() asm volatile("s_barrier" ::: "memory")
#define WAIT_LGKM0() do { asm volatile("s_waitcnt lgkmcnt(0)" ::: "memory"); __builtin_amdgcn_sched_barrier(0); } while (0)
#define WAITVM0() asm volatile("s_waitcnt vmcnt(0)" ::: "memory")

// ---------------- fp32 -> bf16 bulk convert (used for W2) ----------------
__global__ void cvt_kernel(const float* __restrict__ s, unsigned short* __restrict__ d, long ngrp) {
    long i = (long)blockIdx.x * blockDim.x + threadIdx.x;
    long stride = (long)gridDim.x * blockDim.x;
    const float4* s4 = (const float4*)s;
    uint4* d4 = (uint4*)d;
    for (long g = i; g < ngrp; g += stride) {
        float4 a = s4[2 * g], b = s4[2 * g + 1];
        uint4 o;
        o.x = pack2(a.x, a.y); o.y = pack2(a.z, a.w);
        o.z = pack2(b.x, b.y); o.w = pack2(b.z, b.w);
        d4[g] = o;
    }
}

// ---------------- merged: logits (blocks [0,2048)) + W1 cvt (blocks [2048,6144)) ----------------
// Independent workloads co-scheduled: the HBM-bound cvt stream hides the logits dots.
__global__ __launch_bounds__(256) void cvtw1_logits_kernel(
    const float* __restrict__ x, const float* __restrict__ Wr,
    const float* __restrict__ W1, unsigned short* __restrict__ W1b,
    float* __restrict__ wgt, int* __restrict__ eids)
{
    if (blockIdx.x < NTOK / 4) {
        int w = threadIdx.x >> 6, l = threadIdx.x & 63;
        int t = blockIdx.x * 4 + w;
        const float4* xr = (const float4*)(x + (size_t)t * CDIM);
        const float4* Wr4 = (const float4*)Wr;
        float acc[NEXP];
        #pragma unroll
        for (int e = 0; e < NEXP; e++) acc[e] = 0.f;
        #pragma unroll
        for (int i = 0; i < 4; i++) {
            int idx = l + 64 * i;
            float4 xv = xr[idx];
            #pragma unroll
            for (int e = 0; e < NEXP; e++) {
                float4 wv = Wr4[e * 256 + idx];
                acc[e] += xv.x * wv.x + xv.y * wv.y + xv.z * wv.z + xv.w * wv.w;
            }
        }
        #pragma unroll
        for (int e = 0; e < NEXP; e++)
            for (int off = 32; off > 0; off >>= 1) acc[e] += __shfl_down(acc[e], off);
        if (l == 0) {
            int i0 = 0; float l0 = acc[0];
            #pragma unroll
            for (int e = 1; e < NEXP; e++) if (acc[e] > l0) { l0 = acc[e]; i0 = e; }
            int i1 = -1; float l1 = -3.4e38f;
            #pragma unroll
            for (int e = 0; e < NEXP; e++) if (e != i0 && acc[e] > l1) { l1 = acc[e]; i1 = e; }
            float tv = __expf(l1 - l0);
            float den = 1.f + tv;
            wgt[2 * t] = 1.f / den;
            wgt[2 * t + 1] = tv / den;
            eids[t] = i0 | (i1 << 8);
        }
    } else {
        const long ngrp = (long)NEXP * 2 * FDIM * CDIM / 8;
        long bid = blockIdx.x - NTOK / 4;
        long i = bid * blockDim.x + threadIdx.x;
        long stride = (long)(gridDim.x - NTOK / 4) * blockDim.x;
        const float4* s4 = (const float4*)W1;
        uint4* d4 = (uint4*)W1b;
        for (long g = i; g < ngrp; g += stride) {
            float4 a = s4[2 * g], b = s4[2 * g + 1];
            uint4 o;
            o.x = pack2(a.x, a.y); o.y = pack2(a.z, a.w);
            o.z = pack2(b.x, b.y); o.w = pack2(b.z, b.w);
            d4[g] = o;
        }
    }
}

// ---------------- bucket: per-block LDS counters -> 8 global atomics/block ----------------
__global__ __launch_bounds__(256) void bucket_kernel(
    const int* __restrict__ eids, int* __restrict__ list, int* __restrict__ cnt)
{
    __shared__ int lcnt[NEXP];
    __shared__ int lbase[NEXP];
    int t = threadIdx.x;
    if (t < NEXP) lcnt[t] = 0;
    __syncthreads();
    int tok = blockIdx.x * 256 + t;
    int id = eids[tok];
    int e0 = id & 0xff, e1 = (id >> 8) & 0xff;
    int s0 = atomicAdd(&lcnt[e0], 1);
    int s1 = atomicAdd(&lcnt[e1], 1);
    __syncthreads();
    if (t < NEXP) lbase[t] = atomicAdd(&cnt[t], lcnt[t]);
    __syncthreads();
    list[e0 * CAP + lbase[e0] + s0] = 2 * tok;
    list[e1 * CAP + lbase[e1] + s1] = 2 * tok + 1;
}

// ---------------- pack: xg[off_e+s] = bf16(x[tok]); wgs[off_e+s] = wgt[p] ----------------
// 16 rows/block, 16 threads/row; uint4 (16B) stores. off_e computed inline from cnt.
__global__ __launch_bounds__(256) void pack_kernel(
    const float* __restrict__ x, const int* __restrict__ list,
    const int* __restrict__ cnt, const float* __restrict__ wgt,
    unsigned short* __restrict__ xg, float* __restrict__ wgs)
{
    int e = blockIdx.y;
    int cnt_e = cnt[e];
    int s0 = blockIdx.x * 16;
    if (s0 >= cnt_e) return;
    int off_e = exp_off(cnt, e);
    int t = threadIdx.x;
    int sr = s0 + (t >> 4);
    if (sr >= cnt_e) return;
    int p = list[e * CAP + sr];
    int tok = p >> 1;
    if ((t & 15) == 0) wgs[off_e + sr] = wgt[p];
    const float4* src = (const float4*)(x + (size_t)tok * CDIM);
    uint4* dst = (uint4*)(xg + (size_t)(off_e + sr) * CDIM);
    int c = t & 15;
    #pragma unroll
    for (int i = 0; i < 8; i++) {
        float4 a = src[2 * c + i * 32];
        float4 b = src[2 * c + 1 + i * 32];
        uint4 o;
        o.x = pack2(a.x, a.y); o.y = pack2(a.z, a.w);
        o.z = pack2(b.x, b.y); o.w = pack2(b.z, b.w);
        dst[c + i * 16] = o;
    }
}

// ============== GEMM1: dense grouped, 128x64(V+G), BK=64, stage-early drain-late ==============
// Round-10 proven structure (151 us, 910 TF) - loop UNCHANGED.
__global__ __launch_bounds__(256, 2) void gemm1_kernel(
    const unsigned short* __restrict__ xg,    // [NPAIR][CDIM] bf16, slot order
    const unsigned short* __restrict__ W1b,   // [E][2F][CDIM] bf16
    const float* __restrict__ wgs,            // [NPAIR] slot-order router weight
    unsigned short* __restrict__ act,         // [NPAIR][FDIM] bf16, slot order (weighted)
    const int* __restrict__ cnt)
{
    int e = blockIdx.z, nt = blockIdx.x, mt = blockIdx.y;
    int cnt_e = cnt[e];
    if (mt * 128 >= cnt_e) return;
    int off_e = exp_off(cnt, e);

    // LDS 32KB: A k0 [0,8K) | A k1 [8K,16K) | Bv k0/k1 [16K,24K) | Bg k0/k1 [24K,32K)
    __shared__ __align__(16) char lds[32768];

    int t = threadIdx.x, l = t & 63, w = t >> 6;
    int wave_m = w >> 1, wave_n = w & 1;

    int c2s = ((t & 3) * 16) ^ (((t >> 5) & 1) << 5);
    int dst = t * 16;

    const char *sA0, *sA1, *sBv, *sBg;
    {
        int r0 = min(mt * 128 + (t >> 2), cnt_e - 1);
        int r1 = min(mt * 128 + 64 + (t >> 2), cnt_e - 1);
        sA0 = (const char*)xg + (size_t)(off_e + r0) * 2048 + c2s;
        sA1 = (const char*)xg + (size_t)(off_e + r1) * 2048 + c2s;
        int f = nt * 64 + (t >> 2);
        sBv = (const char*)W1b + ((size_t)e * 2 * FDIM + f) * 2048 + c2s;
        sBg = sBv + (size_t)FDIM * 2048;
    }

    int lane_off = (l & 15) * 64 + (((l >> 4) * 16) ^ (((l >> 3) & 1) << 5));
    f32x4 accV[4][2] = {}, accG[4][2] = {};

#define G1_STAGE(KB) do { \
        gload_lds16(sA0 + (KB),      (char*)lds + dst); \
        gload_lds16(sA1 + (KB),      (char*)lds + 4096 + dst); \
        gload_lds16(sA0 + (KB) + 64, (char*)lds + 8192 + dst); \
        gload_lds16(sA1 + (KB) + 64, (char*)lds + 12288 + dst); \
        gload_lds16(sBv + (KB),      (char*)lds + 16384 + dst); \
        gload_lds16(sBv + (KB) + 64, (char*)lds + 20480 + dst); \
        gload_lds16(sBg + (KB),      (char*)lds + 24576 + dst); \
        gload_lds16(sBg + (KB) + 64, (char*)lds + 28672 + dst); \
    } while (0)

    G1_STAGE(0);   // prologue: tile 0

    #pragma unroll
    for (int kt = 0; kt < 16; kt++) {
        WAITVM0();
        BARRIER();

        bf16x8 af[2][4], bv[2][2], bg[2][2];
        #pragma unroll
        for (int h = 0; h < 2; h++) {
            #pragma unroll
            for (int m = 0; m < 4; m++)
                af[h][m] = *(const bf16x8*)((char*)lds + h * 8192 + (wave_m * 4 + m) * 1024 + lane_off);
            #pragma unroll
            for (int n = 0; n < 2; n++) {
                bv[h][n] = *(const bf16x8*)((char*)lds + 16384 + h * 4096 + (wave_n * 2 + n) * 1024 + lane_off);
                bg[h][n] = *(const bf16x8*)((char*)lds + 24576 + h * 4096 + (wave_n * 2 + n) * 1024 + lane_off);
            }
        }
        WAIT_LGKM0();
        BARRIER();           // all waves done reading LDS -> safe to overwrite

        if (kt != 15) { int kb = (kt + 1) * 128; G1_STAGE(kb); }
        __builtin_amdgcn_sched_barrier(0);

        __builtin_amdgcn_s_setprio(1);
        #pragma unroll
        for (int h = 0; h < 2; h++)
            #pragma unroll
            for (int m = 0; m < 4; m++)
                #pragma unroll
                for (int n = 0; n < 2; n++) {
                    accV[m][n] = __builtin_amdgcn_mfma_f32_16x16x32_bf16(af[h][m], bv[h][n], accV[m][n], 0, 0, 0);
                    accG[m][n] = __builtin_amdgcn_mfma_f32_16x16x32_bf16(af[h][m], bg[h][n], accG[m][n], 0, 0, 0);
                }
        __builtin_amdgcn_s_setprio(0);
    }
#undef G1_STAGE

    // epilogue: silu-gate * router weight, bf16 store (slot order)
    int colF = nt * 64 + wave_n * 32 + (l & 15);
    int rowB = mt * 128 + wave_m * 64 + ((l >> 4) * 4);
    #pragma unroll
    for (int m = 0; m < 4; m++) {
        #pragma unroll
        for (int r = 0; r < 4; r++) {
            int srow = rowB + m * 16 + r;
            if (srow < cnt_e) {
                float wsc = wgs[off_e + srow];
                #pragma unroll
                for (int n = 0; n < 2; n++) {
                    float g = accG[m][n][r];
                    float v = accV[m][n][r];
                    float aa = wsc * v * g / (1.f + __expf(-g));
                    act[(size_t)(off_e + srow) * FDIM + colF + n * 16] = f2bf(aa);
                }
            }
        }
    }
}

// ============== GEMM2: dense grouped, 128x128, SPLIT-K=2, BK=64 ==============
__global__ __launch_bounds__(256, 2) void gemm2_kernel(
    const unsigned short* __restrict__ act,   // [NPAIR][FDIM] bf16, slot order (weighted)
    const unsigned short* __restrict__ W2b,   // [E][CDIM][FDIM] bf16
    const int* __restrict__ list, const int* __restrict__ cnt,
    unsigned short* __restrict__ eob0,        // [NPAIR][CDIM] bf16, pair order, K-half 0
    unsigned short* __restrict__ eob1)        // [NPAIR][CDIM] bf16, pair order, K-half 1
{
    int e = blockIdx.z, mt = blockIdx.y;
    int nt = blockIdx.x & 7, kh = blockIdx.x >> 3;
    int cnt_e = cnt[e];
    if (mt * 128 >= cnt_e) return;
    int off_e = exp_off(cnt, e);
    const int* le = list + e * CAP;

    __shared__ __align__(16) char lds[32768];

    int t = threadIdx.x, l = t & 63, w = t >> 6;
    int wave_m = w >> 1, wave_n = w & 1;

    int c2s = ((t & 3) * 16) ^ (((t >> 5) & 1) << 5);
    int dst = t * 16;

    const char *sA0, *sA1, *sB0, *sB1;
    {
        int r0 = min(mt * 128 + (t >> 2), cnt_e - 1);
        int r1 = min(mt * 128 + 64 + (t >> 2), cnt_e - 1);
        size_t khb = (size_t)kh * 2048;   // 1024 elems * 2B
        sA0 = (const char*)act + (size_t)(off_e + r0) * 4096 + khb + c2s;
        sA1 = (const char*)act + (size_t)(off_e + r1) * 4096 + khb + c2s;
        int c0 = nt * 128 + (t >> 2);
        sB0 = (const char*)W2b + ((size_t)e * CDIM + c0) * 4096 + khb + c2s;
        sB1 = sB0 + (size_t)64 * 4096;
    }

    int lane_off = (l & 15) * 64 + (((l >> 4) * 16) ^ (((l >> 3) & 1) << 5));
    f32x4 acc[4][4] = {};

#define G2_STAGE(KB) do { \
        gload_lds16(sA0 + (KB),      (char*)lds + dst); \
        gload_lds16(sA1 + (KB),      (char*)lds + 4096 + dst); \
        gload_lds16(sA0 + (KB) + 64, (char*)lds + 8192 + dst); \
        gload_lds16(sA1 + (KB) + 64, (char*)lds + 12288 + dst); \
        gload_lds16(sB0 + (KB),      (char*)lds + 16384 + dst); \
        gload_lds16(sB1 + (KB),      (char*)lds + 20480 + dst); \
        gload_lds16(sB0 + (KB) + 64, (char*)lds + 24576 + dst); \
        gload_lds16(sB1 + (KB) + 64, (char*)lds + 28672 + dst); \
    } while (0)

    G2_STAGE(0);

    #pragma unroll
    for (int kt = 0; kt < 16; kt++) {
        WAITVM0();
        BARRIER();

        bf16x8 af[2][4], bf[2][4];
        #pragma unroll
        for (int h = 0; h < 2; h++) {
            #pragma unroll
            for (int m = 0; m < 4; m++)
                af[h][m] = *(const bf16x8*)((char*)lds + h * 8192 + (wave_m * 4 + m) * 1024 + lane_off);
            #pragma unroll
            for (int n = 0; n < 4; n++)
                bf[h][n] = *(const bf16x8*)((char*)lds + 16384 + h * 8192 + (wave_n * 4 + n) * 1024 + lane_off);
        }
        WAIT_LGKM0();
        BARRIER();

        if (kt != 15) { int kb = (kt + 1) * 128; G2_STAGE(kb); }
        __builtin_amdgcn_sched_barrier(0);

        __builtin_amdgcn_s_setprio(1);
        #pragma unroll
        for (int h = 0; h < 2; h++)
            #pragma unroll
            for (int m = 0; m < 4; m++)
                #pragma unroll
                for (int n = 0; n < 4; n++)
                    acc[m][n] = __builtin_amdgcn_mfma_f32_16x16x32_bf16(af[h][m], bf[h][n], acc[m][n], 0, 0, 0);
        __builtin_amdgcn_s_setprio(0);
    }
#undef G2_STAGE

    unsigned short* eob = kh ? eob1 : eob0;
    int colC = nt * 128 + wave_n * 64 + (l & 15);
    int rowB = mt * 128 + wave_m * 64 + ((l >> 4) * 4);
    #pragma unroll
    for (int m = 0; m < 4; m++) {
        #pragma unroll
        for (int r = 0; r < 4; r++) {
            int srow = rowB + m * 16 + r;
            if (srow < cnt_e) {
                int p = le[srow];
                #pragma unroll
                for (int n = 0; n < 4; n++)
                    eob[(size_t)p * CDIM + colC + n * 16] = f2bf(acc[m][n][r]);
            }
        }
    }
}

// ---------------- combine: out[t] = sum over {pair0,pair1} x {kh0,kh1}; uint4 reads ----------------
__global__ __launch_bounds__(256) void combine_kernel(
    const unsigned short* __restrict__ eob0, const unsigned short* __restrict__ eob1,
    float* __restrict__ out)
{
    const long NG = (long)NTOK * (CDIM / 8);
    long i = (long)blockIdx.x * blockDim.x + threadIdx.x;
    long stride = (long)gridDim.x * blockDim.x;
    float4* out4 = (float4*)out;
    for (long g = i; g < NG; g += stride) {
        long t = g >> 7;               // CDIM/8 = 128
        long j = g & 127;
        uint4 a0 = ((const uint4*)(eob0 + (size_t)(2 * t) * CDIM))[j];
        uint4 b0 = ((const uint4*)(eob0 + (size_t)(2 * t + 1) * CDIM))[j];
        uint4 a1 = ((const uint4*)(eob1 + (size_t)(2 * t) * CDIM))[j];
        uint4 b1 = ((const uint4*)(eob1 + (size_t)(2 * t + 1) * CDIM))[j];
        float4 o1, o2;
        o1.x = (bflo(a0.x) + bflo(a1.x)) + (bflo(b0.x) + bflo(b1.x));
        o1.y = (bfhi(a0.x) + bfhi(a1.x)) + (bfhi(b0.x) + bfhi(b1.x));
        o1.z = (bflo(a0.y) + bflo(a1.y)) + (bflo(b0.y) + bflo(b1.y));
        o1.w = (bfhi(a0.y) + bfhi(a1.y)) + (bfhi(b0.y) + bfhi(b1.y));
        o2.x = (bflo(a0.z) + bflo(a1.z)) + (bflo(b0.z) + bflo(b1.z));
        o2.y = (bfhi(a0.z) + bfhi(a1.z)) + (bfhi(b0.z) + bfhi(b1.z));
        o2.z = (bflo(a0.w) + bflo(a1.w)) + (bflo(b0.w) + bflo(b1.w));
        o2.w = (bfhi(a0.w) + bfhi(a1.w)) + (bfhi(b0.w) + bfhi(b1.w));
        out4[2 * g] = o1;
        out4[2 * g + 1] = o2;
    }
}

// ---------------- launch ----------------
extern "C" void kernel_launch(void* const* d_in, const int* in_sizes, int n_in,
                              void* d_out, int out_size, void* d_ws, size_t ws_size,
                              hipStream_t stream) {
    const float* x  = (const float*)d_in[0];
    const float* Wr = (const float*)d_in[1];
    const float* W1 = (const float*)d_in[2];
    const float* W2 = (const float*)d_in[3];
    float* out = (float*)d_out;
    char* ws = (char*)d_ws;

    // Workspace (~168.6 MB):
    //   [0, 33.5M)      xg (slot order)      -> eob0 (pair order) after gemm1
    //   [33.5M, 100.7M) W1b                  -> [W2b 33.5M | eob1 33.5M] after gemm1
    //   [100.7M,167.8M) act (slot order)
    //   then list / wgt / wgs / cnt / eids
    const size_t OFF_XG   = 0;
    const size_t OFF_W1B  = OFF_XG  + (size_t)NPAIR * CDIM * 2;           // 33,554,432
    const size_t OFF_ACT  = OFF_W1B + (size_t)NEXP * 2 * FDIM * CDIM * 2; // +67,108,864
    const size_t OFF_LIST = OFF_ACT + (size_t)NPAIR * FDIM * 2;           // +67,108,864
    const size_t OFF_WGT  = OFF_LIST + (size_t)NEXP * CAP * 4;
    const size_t OFF_WGS  = OFF_WGT + (size_t)NPAIR * 4;
    const size_t OFF_CNT  = OFF_WGS + (size_t)NPAIR * 4;
    const size_t OFF_EIDS = OFF_CNT + 32;

    unsigned short* xg  = (unsigned short*)(ws + OFF_XG);
    unsigned short* W1b = (unsigned short*)(ws + OFF_W1B);
    unsigned short* act = (unsigned short*)(ws + OFF_ACT);
    int*   list = (int*)(ws + OFF_LIST);
    float* wgt  = (float*)(ws + OFF_WGT);
    float* wgs  = (float*)(ws + OFF_WGS);
    int*   cnt  = (int*)(ws + OFF_CNT);
    int*   eids = (int*)(ws + OFF_EIDS);
    // overlays (dead-after-gemm1 regions):
    unsigned short* W2b  = (unsigned short*)(ws + OFF_W1B);                               // 33.5 MB
    unsigned short* eob1 = (unsigned short*)(ws + OFF_W1B + (size_t)NPAIR * CDIM * 2);    // 33.5 MB
    unsigned short* eob0 = (unsigned short*)(ws + OFF_XG);                                // 33.5 MB

    hipMemsetAsync(cnt, 0, NEXP * sizeof(int), stream);

    cvtw1_logits_kernel<<<NTOK / 4 + 4096, 256, 0, stream>>>(x, Wr, W1, W1b, wgt, eids);
    bucket_kernel<<<NTOK / 256, 256, 0, stream>>>(eids, list, cnt);
    pack_kernel<<<dim3(256, NEXP), 256, 0, stream>>>(x, list, cnt, wgt, xg, wgs);

    gemm1_kernel<<<dim3(FDIM / 64, MTCAP, NEXP), 256, 0, stream>>>(xg, W1b, wgs, act, cnt);

    cvt_kernel<<<4096, 256, 0, stream>>>(W2, W2b, (long)NEXP * CDIM * FDIM / 8);

    gemm2_kernel<<<dim3(16, MTCAP, NEXP), 256, 0, stream>>>(act, W2b, list, cnt, eob0, eob1);
    combine_kernel<<<2048, 256, 0, stream>>>(eob0, eob1, out);
}